// Round 1
// baseline (205.520 us; speedup 1.0000x reference)
//
#include <hip/hip_runtime.h>

// Problem constants (from setup_inputs)
#define Bn 32
#define An 5
#define Cn 8
#define Hn 96
#define Wn 96
#define On 50
#define CHn 15               // 7 + C
#define HWn (Hn*Wn)          // 9216
#define AHW (An*HWn)         // 46080
#define NCELL (Bn*An*HWn)    // 1474560

// workspace layout (bytes)
#define OFF_CONF 0
#define OFF_MASK NCELL
#define OFF_ENT  (2*NCELL)                 // 2949120 (16-aligned)
#define N_ENT    (Bn*On)                   // 1600
#define OFF_CNT  (OFF_ENT + N_ENT*32)      // 3000320
#define OFF_SCAL (OFF_CNT + Bn*4)          // 3000448 : int n_gt, n_cor
#define OFF_DSUM (OFF_SCAL + 16)           // 3000464 : 8 floats
#define NBLK_C   1024
#define OFF_PART (OFF_DSUM + 32)           // 3000496 : NBLK_C*3 floats
#define TOTAL_BYTES (OFF_PART + NBLK_C*3*4)

struct Entry { int cell; int cls; float tx, ty, tl, tw, tim, tre; };

__device__ __forceinline__ float sigmoidf_(float x) { return 1.0f / (1.0f + expf(-x)); }

// op-for-op copy of the reference iou (argmax tie-break safety)
__device__ __forceinline__ float iou_ref(float gx, float gy, float gl, float gw,
                                         float bx, float by, float bl, float bw) {
    float min_x = fminf(gx - gl * 0.5f, bx - bl * 0.5f);
    float max_x = fmaxf(gx + gl * 0.5f, bx + bl * 0.5f);
    float min_y = fminf(gy - gw * 0.5f, by - bw * 0.5f);
    float max_y = fmaxf(gy + gw * 0.5f, by + bw * 0.5f);
    float union_w = max_y - min_y;
    float union_h = max_x - min_x;
    float inter_w = gw + bw - union_w;
    float inter_l = gl + bl - union_h;
    float inter = (inter_w <= 0.0f || inter_l <= 0.0f) ? 0.0f : inter_w * inter_l;
    float uni = gw * gl + bw * bl - inter;
    return inter / uni;
}

// ---- kernel 1: init workspace (conf=1, everything else 0) ----
__global__ __launch_bounds__(256) void k_init(unsigned int* __restrict__ ws32) {
    const int n = TOTAL_BYTES / 4;
    const int confw = NCELL / 4;
    int stride = gridDim.x * blockDim.x;
    for (int i = blockIdx.x * blockDim.x + threadIdx.x; i < n; i += stride)
        ws32[i] = (i < confw) ? 0x01010101u : 0u;
}

// ---- kernel 2: sequential build_targets (1 thread per batch) ----
__global__ __launch_bounds__(64) void k_build(const float* __restrict__ outp,
                                              const float* __restrict__ tgt,
                                              const float* __restrict__ anch,
                                              unsigned char* __restrict__ conf,
                                              unsigned char* __restrict__ mask,
                                              Entry* __restrict__ ents,
                                              int* __restrict__ cnts,
                                              int* __restrict__ scal) {
    __shared__ int s_cell[Bn][On];
    __shared__ float s_an[10];
    int tid = threadIdx.x;
    if (tid < 10) s_an[tid] = anch[tid];
    __syncthreads();
    int ngt = 0, ncor = 0;
    if (tid < Bn) {
        int b = tid, cnt = 0;
        Entry* my = ents + b * On;
        for (int o = 0; o < On; ++o) {
            const float* t = tgt + (b * On + o) * 7;
            float t0 = t[0];
            if (t0 == 0.0f) break;  // cumprod validity: stop at first cls==0
            float gx = t[1] * (float)Hn, gy = t[2] * (float)Wn;
            float gl = t[3] * (float)Hn, gw = t[4] * (float)Wn;
            float ious[An];
            int best = 0;
            float best_iou = -1.0f;
            #pragma unroll
            for (int aa = 0; aa < An; ++aa) {
                ious[aa] = iou_ref(0.0f, 0.0f, gl, gw, 0.0f, 0.0f, s_an[aa * 2], s_an[aa * 2 + 1]);
                if (ious[aa] > best_iou) { best_iou = ious[aa]; best = aa; }  // first-max
            }
            int ax = (int)gx, ay = (int)gy;
            int cellxy = ax * Wn + ay;
            int cbase = b * AHW + cellxy;
            #pragma unroll
            for (int aa = 0; aa < An; ++aa)
                if (ious[aa] > 0.6f) conf[cbase + aa * HWn] = 0;   // IGNORE_THR
            conf[cbase + best * HWn] = 1;
            mask[cbase + best * HWn] = 1;
            int cell = best * HWn + cellxy;
            // dedupe (last write wins for ch<7; one-hot accumulates -> min cls)
            int slot = -1;
            for (int j = 0; j < cnt; ++j)
                if (s_cell[b][j] == cell) { slot = j; break; }
            float al = s_an[best * 2], aw = s_an[best * 2 + 1];
            Entry e;
            e.cell = cell;
            e.cls = (int)t0;
            e.tx = gx - (float)ax;
            e.ty = gy - (float)ay;
            e.tl = logf(gl / al);
            e.tw = logf(gw / aw);
            e.tim = t[5];
            e.tre = t[6];
            if (slot >= 0) {
                int oldc = my[slot].cls;
                if (oldc < e.cls) e.cls = oldc;
                my[slot] = e;
            } else {
                s_cell[b][cnt] = cell;
                my[cnt] = e;
                ++cnt;
            }
            // prediction at this cell (fmap_preds)
            const float* p = outp + ((b * An + best) * CHn) * HWn + cellxy;
            float px = sigmoidf_(p[0]) + (float)ax;
            float py = sigmoidf_(p[HWn]) + (float)ay;
            float pl = expf(p[2 * HWn]) * al;
            float pw = expf(p[3 * HWn]) * aw;
            float pc = sigmoidf_(p[6 * HWn]);
            float piou = iou_ref(gx, gy, gl, gw, px, py, pl, pw);
            ngt++;
            if (piou > 0.5f && pc > 0.5f) ncor++;
        }
        cnts[b] = cnt;
    }
    // wave(64)-wide reduce; lanes >=32 contribute 0
    #pragma unroll
    for (int off = 32; off > 0; off >>= 1) {
        ngt += __shfl_down(ngt, off);
        ncor += __shfl_down(ncor, off);
    }
    if (tid == 0) { scal[0] = ngt; scal[1] = ncor; }
}

// ---- kernel 3: dense fm-weighted BCE over all cells (deterministic partials) ----
__global__ __launch_bounds__(256) void k_dense(const float* __restrict__ outp,
                                               const unsigned char* __restrict__ conf,
                                               const unsigned char* __restrict__ mask,
                                               float* __restrict__ partials) {
    float s_bce = 0.0f, s_nf = 0.0f, s_nt = 0.0f;
    int stride = gridDim.x * blockDim.x;
    for (int i = blockIdx.x * blockDim.x + threadIdx.x; i < NCELL; i += stride) {
        int m = mask[i], c = conf[i];
        s_nt += (float)m;
        if (c != m) {  // false_mask
            int b = i / AHW;
            int rem = i - b * AHW;
            int a = rem / HWn;
            int xy = rem - a * HWn;
            float v = outp[((b * An + a) * CHn + 6) * HWn + xy];
            // t = m: contribution = min(softplus(-v),100) if m else min(softplus(v),100)
            float sp = m ? log1pf(expf(-v)) : log1pf(expf(v));
            s_bce += fminf(sp, 100.0f);
            s_nf += 1.0f;
        }
    }
    __shared__ float red[256];
    int tid = threadIdx.x;
#define BLK_RED(val, dstidx)                                              \
    red[tid] = (val); __syncthreads();                                    \
    for (int off = 128; off > 0; off >>= 1) {                             \
        if (tid < off) red[tid] += red[tid + off];                        \
        __syncthreads();                                                  \
    }                                                                     \
    if (tid == 0) partials[blockIdx.x * 3 + (dstidx)] = red[0];           \
    __syncthreads();
    BLK_RED(s_bce, 0)
    BLK_RED(s_nf, 1)
    BLK_RED(s_nt, 2)
#undef BLK_RED
}

// ---- kernel 4: sparse per-masked-cell losses ----
__global__ __launch_bounds__(256) void k_sparse(const float* __restrict__ outp,
                                                const Entry* __restrict__ ents,
                                                const int* __restrict__ cnts,
                                                float* __restrict__ dsum) {
    float s0 = 0, s1 = 0, s2 = 0, s3 = 0, s4 = 0, s5 = 0, s6 = 0, s7 = 0;
    for (int idx = threadIdx.x; idx < N_ENT; idx += 256) {
        int b = idx / On, j = idx - b * On;
        if (j >= cnts[b]) continue;
        Entry e = ents[idx];
        int a = e.cell / HWn, xy = e.cell - a * HWn;
        const float* p = outp + ((b * An + a) * CHn) * HWn + xy;
        float o0 = p[0], o1 = p[HWn], o2 = p[2 * HWn], o3 = p[3 * HWn];
        float o4 = p[4 * HWn], o5 = p[5 * HWn], o6 = p[6 * HWn];
        float d;
        d = sigmoidf_(o0) - e.tx; s0 += d * d;
        d = sigmoidf_(o1) - e.ty; s1 += d * d;
        d = o2 - e.tl;            s2 += d * d;
        d = o3 - e.tw;            s3 += d * d;
        d = o4 - e.tim;           s4 += d * d;
        d = o5 - e.tre;           s5 += d * d;
        s6 += fminf(log1pf(expf(-o6)), 100.0f);  // m-weighted BCE term (t=1)
        // loss_cls: logsumexp(sigmoid(cls logits)) - sigmoid(cls logit)[label]
        float sc[Cn];
        float mx = -1e30f;
        #pragma unroll
        for (int k = 0; k < Cn; ++k) {
            sc[k] = sigmoidf_(p[(7 + k) * HWn]);
            mx = fmaxf(mx, sc[k]);
        }
        float se = 0.0f;
        #pragma unroll
        for (int k = 0; k < Cn; ++k) se += expf(sc[k] - mx);
        float lse = mx + logf(se);
        s7 += lse - sc[e.cls];
    }
    __shared__ float red[256];
    int tid = threadIdx.x;
#define BLK_RED(val, dstidx)                                              \
    red[tid] = (val); __syncthreads();                                    \
    for (int off = 128; off > 0; off >>= 1) {                             \
        if (tid < off) red[tid] += red[tid + off];                        \
        __syncthreads();                                                  \
    }                                                                     \
    if (tid == 0) dsum[dstidx] = red[0];                                  \
    __syncthreads();
    BLK_RED(s0, 0) BLK_RED(s1, 1) BLK_RED(s2, 2) BLK_RED(s3, 3)
    BLK_RED(s4, 4) BLK_RED(s5, 5) BLK_RED(s6, 6) BLK_RED(s7, 7)
#undef BLK_RED
}

// ---- kernel 5: finalize ----
__global__ __launch_bounds__(256) void k_final(const float* __restrict__ partials,
                                               const float* __restrict__ dsum,
                                               const int* __restrict__ scal,
                                               float* __restrict__ op) {
    float a0 = 0, a1 = 0, a2 = 0;
    int tid = threadIdx.x;
    for (int i = tid; i < NBLK_C; i += 256) {
        a0 += partials[i * 3 + 0];
        a1 += partials[i * 3 + 1];
        a2 += partials[i * 3 + 2];
    }
    __shared__ float r0[256], r1[256], r2[256];
    r0[tid] = a0; r1[tid] = a1; r2[tid] = a2;
    __syncthreads();
    for (int off = 128; off > 0; off >>= 1) {
        if (tid < off) {
            r0[tid] += r0[tid + off];
            r1[tid] += r1[tid + off];
            r2[tid] += r2[tid + off];
        }
        __syncthreads();
    }
    if (tid == 0) {
        float fmbce = r0[0], nf = r1[0], nt = r2[0];
        float loss_conf = fmbce / nf + dsum[6] / nt;
        float loss_cls = (1.0f / (float)Bn) * dsum[7] / nt;
        float loss = (dsum[0] + dsum[1] + dsum[3] + dsum[2] + dsum[4] + dsum[5]) / nt
                     + loss_conf + loss_cls;
        op[0] = loss;
        op[1] = (float)scal[0];
        op[2] = (float)scal[1];
    }
}

extern "C" void kernel_launch(void* const* d_in, const int* in_sizes, int n_in,
                              void* d_out, int out_size, void* d_ws, size_t ws_size,
                              hipStream_t stream) {
    const float* outp = (const float*)d_in[0];
    const float* tgt  = (const float*)d_in[1];
    const float* anch = (const float*)d_in[2];
    char* ws = (char*)d_ws;
    unsigned char* conf = (unsigned char*)(ws + OFF_CONF);
    unsigned char* mask = (unsigned char*)(ws + OFF_MASK);
    Entry* ents = (Entry*)(ws + OFF_ENT);
    int* cnts = (int*)(ws + OFF_CNT);
    int* scal = (int*)(ws + OFF_SCAL);
    float* dsum = (float*)(ws + OFF_DSUM);
    float* partials = (float*)(ws + OFF_PART);
    float* op = (float*)d_out;

    hipLaunchKernelGGL(k_init, dim3(512), dim3(256), 0, stream, (unsigned int*)ws);
    hipLaunchKernelGGL(k_build, dim3(1), dim3(64), 0, stream,
                       outp, tgt, anch, conf, mask, ents, cnts, scal);
    hipLaunchKernelGGL(k_dense, dim3(NBLK_C), dim3(256), 0, stream, outp, conf, mask, partials);
    hipLaunchKernelGGL(k_sparse, dim3(1), dim3(256), 0, stream, outp, ents, cnts, dsum);
    hipLaunchKernelGGL(k_final, dim3(1), dim3(256), 0, stream, partials, dsum, scal, op);
}

// Round 2
// 41.642 us; speedup vs baseline: 4.9355x; 4.9355x over previous
//
#include <hip/hip_runtime.h>

// Problem constants (from setup_inputs)
#define Bn 32
#define An 5
#define Cn 8
#define Hn 96
#define Wn 96
#define On 50
#define CHn 15               // 7 + C
#define HWn (Hn*Wn)          // 9216
#define AHW (An*HWn)         // 46080
#define NCELL (Bn*An*HWn)    // 1474560

#define NBLK_D 256           // dense-BCE blocks

// workspace layout (bytes)
#define OFF_CONF 0
#define OFF_MASK NCELL
#define OFF_BPART (2*NCELL)                // Bn*8 floats = 1024 B
#define OFF_SCAL  (OFF_BPART + Bn*8*4)     // 3 ints: ngt, ncor, nt (pad 16)
#define OFF_PART  (OFF_SCAL + 16)          // NBLK_D*2 floats: bce, nf
#define TOTAL_BYTES (OFF_PART + NBLK_D*2*4)

__device__ __forceinline__ float sigmoidf_(float x) { return 1.0f / (1.0f + expf(-x)); }

// op-for-op copy of the reference iou (argmax tie-break safety)
__device__ __forceinline__ float iou_ref(float gx, float gy, float gl, float gw,
                                         float bx, float by, float bl, float bw) {
    float min_x = fminf(gx - gl * 0.5f, bx - bl * 0.5f);
    float max_x = fmaxf(gx + gl * 0.5f, bx + bl * 0.5f);
    float min_y = fminf(gy - gw * 0.5f, by - bw * 0.5f);
    float max_y = fmaxf(gy + gw * 0.5f, by + bw * 0.5f);
    float union_w = max_y - min_y;
    float union_h = max_x - min_x;
    float inter_w = gw + bw - union_w;
    float inter_l = gl + bl - union_h;
    float inter = (inter_w <= 0.0f || inter_l <= 0.0f) ? 0.0f : inter_w * inter_l;
    float uni = gw * gl + bw * bl - inter;
    return inter / uni;
}

// ---- kernel 1: init workspace (conf=1, everything else 0) ----
__global__ __launch_bounds__(256) void k_init(unsigned int* __restrict__ ws32) {
    const int n = TOTAL_BYTES / 4;
    const int confw = NCELL / 4;
    int stride = gridDim.x * blockDim.x;
    for (int i = blockIdx.x * blockDim.x + threadIdx.x; i < n; i += stride)
        ws32[i] = (i < confw) ? 0x01010101u : 0u;
}

// ---- kernel 2: per-batch build + sparse losses (1 block per batch, 1 wave) ----
__global__ __launch_bounds__(64) void k_batch(const float* __restrict__ outp,
                                              const float* __restrict__ tgt,
                                              const float* __restrict__ anch,
                                              unsigned char* __restrict__ conf,
                                              unsigned char* __restrict__ mask,
                                              float* __restrict__ bpart,
                                              int* __restrict__ scal) {
    const int b = blockIdx.x;
    const int lane = threadIdx.x;
    __shared__ float s_an[10];
    __shared__ int s_cellxy[On], s_best[On], s_ign[On], s_cls[On];
    __shared__ float s_ef[On][6];
    __shared__ int s_dcell[On], s_didx[On], s_dcls[On];
    if (lane < 10) s_an[lane] = anch[lane];
    __syncthreads();

    // ---- phase A: parallel per-entry compute (lane o = object o) ----
    const float* t = tgt + (size_t)(b * On + lane) * 7;
    float t0 = 0.0f;
    if (lane < On) t0 = t[0];
    unsigned long long vm = __ballot(lane < On && t0 != 0.0f);
    int nv = __ffsll(~vm) - 1;  // cumprod validity: first zero terminates

    bool correct = false;
    if (lane < nv) {
        float gx = t[1] * (float)Hn, gy = t[2] * (float)Wn;
        float gl = t[3] * (float)Hn, gw = t[4] * (float)Wn;
        float best_iou = -1.0f;
        int best = 0, ign = 0;
        #pragma unroll
        for (int a = 0; a < An; ++a) {
            float ia = iou_ref(0.0f, 0.0f, gl, gw, 0.0f, 0.0f, s_an[2 * a], s_an[2 * a + 1]);
            if (ia > best_iou) { best_iou = ia; best = a; }  // first-max tie-break
            if (ia > 0.6f) ign |= (1 << a);                  // IGNORE_THR
        }
        int ax = (int)gx, ay = (int)gy;
        int cellxy = ax * Wn + ay;
        float al = s_an[2 * best], aw = s_an[2 * best + 1];
        s_cellxy[lane] = cellxy;
        s_best[lane] = best;
        s_ign[lane] = ign;
        s_cls[lane] = (int)t0;
        s_ef[lane][0] = gx - (float)ax;
        s_ef[lane][1] = gy - (float)ay;
        s_ef[lane][2] = logf(gl / al);
        s_ef[lane][3] = logf(gw / aw);
        s_ef[lane][4] = t[5];
        s_ef[lane][5] = t[6];
        const float* p = outp + ((size_t)(b * An + best) * CHn) * HWn + cellxy;
        float px = sigmoidf_(p[0]) + (float)ax;
        float py = sigmoidf_(p[HWn]) + (float)ay;
        float pl = expf(p[2 * HWn]) * al;
        float pw = expf(p[3 * HWn]) * aw;
        float pc = sigmoidf_(p[6 * HWn]);
        float piou = iou_ref(gx, gy, gl, gw, px, py, pl, pw);
        correct = (piou > 0.5f) && (pc > 0.5f);
    }
    int ncor = __popcll(__ballot(correct));
    __syncthreads();

    // ---- phase B: sequential replay (uniform wave loop, LDS-only chain) ----
    int cnt = 0;
    for (int o = 0; o < nv; ++o) {
        int cellxy = s_cellxy[o], best = s_best[o], ign = s_ign[o];
        if (lane == 0) {
            int cbase = b * AHW + cellxy;
            #pragma unroll
            for (int a = 0; a < An; ++a)
                if ((ign >> a) & 1) conf[cbase + a * HWn] = 0;
            conf[cbase + best * HWn] = 1;   // same-thread store order = program order
            mask[cbase + best * HWn] = 1;
        }
        int cell = best * HWn + cellxy;
        unsigned long long f = __ballot(lane < cnt && s_dcell[lane] == cell);
        if (f) {  // uniform: last write wins for fields, one-hot accumulates -> min cls
            int slot = __ffsll(f) - 1;
            if (lane == 0) {
                s_didx[slot] = o;
                s_dcls[slot] = min(s_dcls[slot], s_cls[o]);
            }
        } else {
            if (lane == 0) { s_dcell[cnt] = cell; s_didx[cnt] = o; s_dcls[cnt] = s_cls[o]; }
            ++cnt;
        }
        __syncthreads();
    }

    // ---- phase C: parallel sparse losses over deduped masked cells ----
    float s[8] = {0, 0, 0, 0, 0, 0, 0, 0};
    if (lane < cnt) {
        int i = s_didx[lane];
        int cell = s_dcell[lane];
        int a = cell / HWn, xy = cell - a * HWn;
        const float* p = outp + ((size_t)(b * An + a) * CHn) * HWn + xy;
        float o0 = p[0], o1 = p[HWn], o2 = p[2 * HWn], o3 = p[3 * HWn];
        float o4 = p[4 * HWn], o5 = p[5 * HWn], o6 = p[6 * HWn];
        float d;
        d = sigmoidf_(o0) - s_ef[i][0]; s[0] = d * d;
        d = sigmoidf_(o1) - s_ef[i][1]; s[1] = d * d;
        d = o2 - s_ef[i][2];            s[2] = d * d;
        d = o3 - s_ef[i][3];            s[3] = d * d;
        d = o4 - s_ef[i][4];            s[4] = d * d;
        d = o5 - s_ef[i][5];            s[5] = d * d;
        s[6] = fminf(log1pf(expf(-o6)), 100.0f);  // m-weighted BCE (t=1)
        float sc[Cn];
        float mx = -1e30f;
        #pragma unroll
        for (int k = 0; k < Cn; ++k) {
            sc[k] = sigmoidf_(p[(7 + k) * HWn]);
            mx = fmaxf(mx, sc[k]);
        }
        float se = 0.0f;
        #pragma unroll
        for (int k = 0; k < Cn; ++k) se += expf(sc[k] - mx);
        s[7] = mx + logf(se) - sc[s_dcls[lane]];  // ce at label = min cls
    }
    #pragma unroll
    for (int off = 32; off > 0; off >>= 1) {
        #pragma unroll
        for (int k = 0; k < 8; ++k) s[k] += __shfl_down(s[k], off);
    }
    if (lane == 0) {
        #pragma unroll
        for (int k = 0; k < 8; ++k) bpart[b * 8 + k] = s[k];
        atomicAdd(&scal[0], nv);    // n_gt   (int: deterministic)
        atomicAdd(&scal[1], ncor);  // n_cor
        atomicAdd(&scal[2], cnt);   // nt
    }
}

// ---- kernel 3: dense fm-weighted BCE over all cells (vectorized) ----
__global__ __launch_bounds__(256) void k_dense(const float* __restrict__ outp,
                                               const unsigned char* __restrict__ conf,
                                               const unsigned char* __restrict__ mask,
                                               float* __restrict__ partials) {
    float s_bce = 0.0f, s_nf = 0.0f;
    const int nq = NCELL / 4;
    int stride = gridDim.x * blockDim.x;
    for (int q = blockIdx.x * blockDim.x + threadIdx.x; q < nq; q += stride) {
        int i = q * 4;
        uchar4 c4 = ((const uchar4*)conf)[q];
        uchar4 m4 = ((const uchar4*)mask)[q];
        int plane = i / HWn;               // b*An + a  (4-cell chunk never crosses a plane)
        int xy = i - plane * HWn;
        const float4 v4 = *(const float4*)(outp + ((size_t)plane * CHn + 6) * HWn + xy);
        #define CELL(cc, mm, vv)                                           \
        if ((cc) != (mm)) {                                                \
            float sp = log1pf(expf((mm) ? -(vv) : (vv)));                  \
            s_bce += fminf(sp, 100.0f);                                    \
            s_nf += 1.0f;                                                  \
        }
        CELL(c4.x, m4.x, v4.x)
        CELL(c4.y, m4.y, v4.y)
        CELL(c4.z, m4.z, v4.z)
        CELL(c4.w, m4.w, v4.w)
        #undef CELL
    }
    __shared__ float red[2][256];
    int tid = threadIdx.x;
    red[0][tid] = s_bce;
    red[1][tid] = s_nf;
    __syncthreads();
    for (int off = 128; off > 0; off >>= 1) {
        if (tid < off) {
            red[0][tid] += red[0][tid + off];
            red[1][tid] += red[1][tid + off];
        }
        __syncthreads();
    }
    if (tid == 0) {
        partials[blockIdx.x * 2 + 0] = red[0][0];
        partials[blockIdx.x * 2 + 1] = red[1][0];
    }
}

// ---- kernel 4: finalize ----
__global__ __launch_bounds__(256) void k_final(const float* __restrict__ partials,
                                               const float* __restrict__ bpart,
                                               const int* __restrict__ scal,
                                               float* __restrict__ op) {
    int tid = threadIdx.x;
    float a0 = 0.0f, a1 = 0.0f;
    for (int i = tid; i < NBLK_D; i += 256) {
        a0 += partials[2 * i + 0];
        a1 += partials[2 * i + 1];
    }
    __shared__ float r[2][256];
    __shared__ float ds[8];
    r[0][tid] = a0;
    r[1][tid] = a1;
    if (tid < 8) {  // 8 lanes each sum one loss component over 32 batches
        float t = 0.0f;
        for (int b = 0; b < Bn; ++b) t += bpart[b * 8 + tid];
        ds[tid] = t;
    }
    __syncthreads();
    for (int off = 128; off > 0; off >>= 1) {
        if (tid < off) {
            r[0][tid] += r[0][tid + off];
            r[1][tid] += r[1][tid + off];
        }
        __syncthreads();
    }
    if (tid == 0) {
        float fmbce = r[0][0], nf = r[1][0];
        float nt = (float)scal[2];
        float loss_conf = fmbce / nf + ds[6] / nt;
        float loss_cls = (1.0f / (float)Bn) * ds[7] / nt;
        float loss = (ds[0] + ds[1] + ds[3] + ds[2] + ds[4] + ds[5]) / nt
                     + loss_conf + loss_cls;
        op[0] = loss;
        op[1] = (float)scal[0];
        op[2] = (float)scal[1];
    }
}

extern "C" void kernel_launch(void* const* d_in, const int* in_sizes, int n_in,
                              void* d_out, int out_size, void* d_ws, size_t ws_size,
                              hipStream_t stream) {
    const float* outp = (const float*)d_in[0];
    const float* tgt  = (const float*)d_in[1];
    const float* anch = (const float*)d_in[2];
    char* ws = (char*)d_ws;
    unsigned char* conf = (unsigned char*)(ws + OFF_CONF);
    unsigned char* mask = (unsigned char*)(ws + OFF_MASK);
    float* bpart = (float*)(ws + OFF_BPART);
    int* scal = (int*)(ws + OFF_SCAL);
    float* partials = (float*)(ws + OFF_PART);
    float* op = (float*)d_out;

    hipLaunchKernelGGL(k_init, dim3(512), dim3(256), 0, stream, (unsigned int*)ws);
    hipLaunchKernelGGL(k_batch, dim3(Bn), dim3(64), 0, stream,
                       outp, tgt, anch, conf, mask, bpart, scal);
    hipLaunchKernelGGL(k_dense, dim3(NBLK_D), dim3(256), 0, stream, outp, conf, mask, partials);
    hipLaunchKernelGGL(k_final, dim3(1), dim3(256), 0, stream, partials, bpart, scal, op);
}

// Round 3
// 19.075 us; speedup vs baseline: 10.7741x; 2.1830x over previous
//
#include <hip/hip_runtime.h>

// Problem constants (from setup_inputs)
#define Bn 32
#define An 5
#define Cn 8
#define Hn 96
#define Wn 96
#define On 50
#define CHn 15               // 7 + C
#define HWn (Hn*Wn)          // 9216
#define NCELL (Bn*An*HWn)    // 1474560
#define NQ (NCELL/4)         // 368640 float4 chunks of the conf channel
#define QPP (HWn/4)          // 2304 float4 per (b,a) plane

#define NBLK_D 224
#define GRID1 (Bn + NBLK_D)  // 256 blocks

// workspace layout (bytes) — tiny; every word written before read, no init pass
#define OFF_BPART 0                   // Bn*13 floats: s0..s7, bcorr, nfcorr, nv, ncor, cnt
#define OFF_PART  (Bn*13*4)           // NBLK_D floats: dense softplus partials

__device__ __forceinline__ float sigmoidf_(float x) { return 1.0f / (1.0f + expf(-x)); }
__device__ __forceinline__ float sp100(float v) {    // min(softplus(v),100) == -clip(log(1-sigmoid(v)),-100)
    return fminf(log1pf(expf(v)), 100.0f);
}

// op-for-op copy of the reference iou (argmax tie-break safety)
__device__ __forceinline__ float iou_ref(float gx, float gy, float gl, float gw,
                                         float bx, float by, float bl, float bw) {
    float min_x = fminf(gx - gl * 0.5f, bx - bl * 0.5f);
    float max_x = fmaxf(gx + gl * 0.5f, bx + bl * 0.5f);
    float min_y = fminf(gy - gw * 0.5f, by - bw * 0.5f);
    float max_y = fmaxf(gy + gw * 0.5f, by + bw * 0.5f);
    float union_w = max_y - min_y;
    float union_h = max_x - min_x;
    float inter_w = gw + bw - union_w;
    float inter_l = gl + bl - union_h;
    float inter = (inter_w <= 0.0f || inter_l <= 0.0f) ? 0.0f : inter_w * inter_l;
    float uni = gw * gl + bw * bl - inter;
    return inter / uni;
}

// ---- kernel 1: fused batch-role (blocks 0..31) + dense-role (blocks 32..255) ----
__global__ __launch_bounds__(256) void k_main(const float* __restrict__ outp,
                                              const float* __restrict__ tgt,
                                              const float* __restrict__ anch,
                                              float* __restrict__ bpart,
                                              float* __restrict__ partials) {
    const int blk = blockIdx.x;
    const int tid = threadIdx.x;

    if (blk >= Bn) {
        // ======== dense role: sum min(softplus(conf_logit),100) over ALL cells ========
        float s = 0.0f;
        for (int q = (blk - Bn) * 256 + tid; q < NQ; q += NBLK_D * 256) {
            int plane = q / QPP;                  // b*An + a
            int r = q - plane * QPP;
            const float4 v = *(const float4*)(outp + ((size_t)plane * CHn + 6) * HWn + (size_t)r * 4);
            s += sp100(v.x) + sp100(v.y) + sp100(v.z) + sp100(v.w);
        }
        __shared__ float red[256];
        red[tid] = s;
        __syncthreads();
        for (int off = 128; off > 0; off >>= 1) {
            if (tid < off) red[tid] += red[tid + off];
            __syncthreads();
        }
        if (tid == 0) partials[blk - Bn] = red[0];
        return;
    }

    // ======== batch role: wave 0 only, zero barriers, zero LDS ========
    if (tid >= 64) return;
    const int b = blk;
    const int o = tid;

    float anv[10];
    #pragma unroll
    for (int k = 0; k < 10; ++k) anv[k] = anch[k];

    const float* t = tgt + (size_t)(b * On + o) * 7;
    float t0 = (o < On) ? t[0] : 0.0f;
    unsigned long long vm = __ballot(t0 != 0.0f);
    int nv = __ffsll(~vm) - 1;          // cumprod validity: first zero terminates
    bool valid = o < nv;

    int best = 0, ign = 0, cellxy = -1, cls = 0;
    float ef0 = 0, ef1 = 0, ef2 = 0, ef3 = 0, ef4 = 0, ef5 = 0;
    float o0 = 0, o1 = 0, o2 = 0, o3 = 0, o4 = 0, o5 = 0, o6 = 0;
    bool correct = false;
    if (valid) {
        float gx = t[1] * (float)Hn, gy = t[2] * (float)Wn;
        float gl = t[3] * (float)Hn, gw = t[4] * (float)Wn;
        float bi = -1.0f, al = anv[0], aw = anv[1];
        #pragma unroll
        for (int a = 0; a < An; ++a) {
            float ia = iou_ref(0.0f, 0.0f, gl, gw, 0.0f, 0.0f, anv[2 * a], anv[2 * a + 1]);
            if (ia > bi) { bi = ia; best = a; al = anv[2 * a]; aw = anv[2 * a + 1]; }  // first-max
            if (ia > 0.6f) ign |= (1 << a);   // IGNORE_THR
        }
        int ax = (int)gx, ay = (int)gy;
        cellxy = ax * Wn + ay;
        ef0 = gx - (float)ax;
        ef1 = gy - (float)ay;
        ef2 = logf(gl / al);
        ef3 = logf(gw / aw);
        ef4 = t[5];
        ef5 = t[6];
        cls = (int)t0;
        const float* p = outp + ((size_t)(b * An + best) * CHn) * HWn + cellxy;
        o0 = p[0]; o1 = p[HWn]; o2 = p[2 * HWn]; o3 = p[3 * HWn];
        o4 = p[4 * HWn]; o5 = p[5 * HWn]; o6 = p[6 * HWn];
        float px = sigmoidf_(o0) + (float)ax;
        float py = sigmoidf_(o1) + (float)ay;
        float pl = expf(o2) * al;
        float pw = expf(o3) * aw;
        float pc = sigmoidf_(o6);
        float piou = iou_ref(gx, gy, gl, gw, px, py, pl, pw);
        correct = (piou > 0.5f) && (pc > 0.5f);
    }
    int ncor = __popcll(__ballot(correct));

    // one shuffle scan resolves: last-writer dedup (ts fields), min-cls (one-hot argmax),
    // per-cellxy leader, and the order-dependent conf/mask state machine
    int keyt = best * HWn + cellxy;
    bool has_later = false, has_earlier = false;
    int clsmin = cls, cbits = 0x1F, mbits = 0;
    for (int j = 0; j < nv; ++j) {
        int jc = __shfl(cellxy, j);
        int jb = __shfl(best, j);
        int ji = __shfl(ign, j);
        int jcl = __shfl(cls, j);
        if (valid) {
            if (jb * HWn + jc == keyt) {
                if (j > o) has_later = true;
                clsmin = min(clsmin, jcl);
            }
            if (jc == cellxy) {
                if (j < o) has_earlier = true;
                cbits = (cbits & ~ji) | (1 << jb);   // ignore-clear then best-set, in order
                mbits |= (1 << jb);
            }
        }
    }
    bool is_last = valid && !has_later;      // represents the deduped masked cell
    bool is_leader = valid && !has_earlier;  // owns this cellxy's conf-state corrections
    int cnt = __popcll(__ballot(is_last));   // nt

    // sparse per-masked-cell losses (last writer's fields, min cls label)
    float s0 = 0, s1 = 0, s2 = 0, s3 = 0, s4 = 0, s5 = 0, s6 = 0, s7 = 0;
    if (is_last) {
        float d;
        d = sigmoidf_(o0) - ef0; s0 = d * d;
        d = sigmoidf_(o1) - ef1; s1 = d * d;
        d = o2 - ef2;            s2 = d * d;
        d = o3 - ef3;            s3 = d * d;
        d = o4 - ef4;            s4 = d * d;
        d = o5 - ef5;            s5 = d * d;
        s6 = sp100(-o6);                         // m-weighted BCE (t=1)
        const float* p = outp + ((size_t)(b * An + best) * CHn) * HWn + cellxy;
        float sc[Cn], mx = -1e30f;
        #pragma unroll
        for (int k = 0; k < Cn; ++k) {
            sc[k] = sigmoidf_(p[(7 + k) * HWn]);
            mx = fmaxf(mx, sc[k]);
        }
        float se = 0.0f, sct = 0.0f;
        #pragma unroll
        for (int k = 0; k < Cn; ++k) {
            se += expf(sc[k] - mx);
            if (k == clsmin) sct = sc[k];        // unrolled select (no scratch)
        }
        s7 = mx + logf(se) - sct;
    }

    // dense-BCE corrections for touched (cellxy, anchor) cells
    float bcorr = 0.0f, nfcorr = 0.0f;
    if (is_leader) {
        const float* pc6 = outp + ((size_t)(b * An) * CHn + 6) * HWn + cellxy;
        #pragma unroll
        for (int a = 0; a < An; ++a) {
            int c = (cbits >> a) & 1, m = (mbits >> a) & 1;
            if (c == m) {                        // (1,1) or (0,0): not in false_mask
                float v = pc6[(size_t)a * CHn * HWn];
                bcorr -= sp100(v);
                nfcorr -= 1.0f;
            } else if (m == 1) {                 // (0,1): in false_mask with t=1
                float v = pc6[(size_t)a * CHn * HWn];
                bcorr += sp100(-v) - sp100(v);
            }                                    // (1,0): same as untouched base — no-op
        }
    }

    float r[10] = {s0, s1, s2, s3, s4, s5, s6, s7, bcorr, nfcorr};
    #pragma unroll
    for (int off = 32; off > 0; off >>= 1) {
        #pragma unroll
        for (int k = 0; k < 10; ++k) r[k] += __shfl_down(r[k], off);
    }
    if (o == 0) {
        float* dst = bpart + b * 13;
        #pragma unroll
        for (int k = 0; k < 10; ++k) dst[k] = r[k];
        dst[10] = (float)nv;
        dst[11] = (float)ncor;
        dst[12] = (float)cnt;
    }
}

// ---- kernel 2: finalize ----
__global__ __launch_bounds__(256) void k_final(const float* __restrict__ partials,
                                               const float* __restrict__ bpart,
                                               float* __restrict__ op) {
    int tid = threadIdx.x;
    float a0 = (tid < NBLK_D) ? partials[tid] : 0.0f;
    __shared__ float red[256];
    __shared__ float ds[13];
    if (tid < 13) {
        float s = 0.0f;
        for (int b = 0; b < Bn; ++b) s += bpart[b * 13 + tid];
        ds[tid] = s;
    }
    red[tid] = a0;
    __syncthreads();
    for (int off = 128; off > 0; off >>= 1) {
        if (tid < off) red[tid] += red[tid + off];
        __syncthreads();
    }
    if (tid == 0) {
        float fmbce = red[0] + ds[8];            // base (all cells, t=0) + corrections
        float nf = (float)NCELL + ds[9];
        float nt = ds[12];
        float loss_conf = fmbce / nf + ds[6] / nt;
        float loss_cls = (1.0f / (float)Bn) * ds[7] / nt;
        float loss = (ds[0] + ds[1] + ds[3] + ds[2] + ds[4] + ds[5]) / nt
                     + loss_conf + loss_cls;
        op[0] = loss;
        op[1] = ds[10];   // n_gt
        op[2] = ds[11];   // n_cor
    }
}

extern "C" void kernel_launch(void* const* d_in, const int* in_sizes, int n_in,
                              void* d_out, int out_size, void* d_ws, size_t ws_size,
                              hipStream_t stream) {
    const float* outp = (const float*)d_in[0];
    const float* tgt  = (const float*)d_in[1];
    const float* anch = (const float*)d_in[2];
    char* ws = (char*)d_ws;
    float* bpart = (float*)(ws + OFF_BPART);
    float* partials = (float*)(ws + OFF_PART);
    float* op = (float*)d_out;

    hipLaunchKernelGGL(k_main, dim3(GRID1), dim3(256), 0, stream,
                       outp, tgt, anch, bpart, partials);
    hipLaunchKernelGGL(k_final, dim3(1), dim3(256), 0, stream, partials, bpart, op);
}